// Round 6
// baseline (259.577 us; speedup 1.0000x reference)
//
#include <hip/hip_runtime.h>

#define NAGENTS 8
#define NM 128          // NAGENTS*MITEMS
#define MENU 256
#define SFULL 257       // MENU + null entry

// Raw barrier: wait LDS ops only (NO vmcnt drain — keeps payload loads and
// copy-out stores in flight across phases).
#define BAR() asm volatile("s_waitcnt lgkmcnt(0)\n\ts_barrier" ::: "memory")

__device__ __forceinline__ float wredmax(float v) {
#pragma unroll
    for (int o = 32; o; o >>= 1) v = fmaxf(v, __shfl_xor(v, o));
    return v;
}
__device__ __forceinline__ float wredsum(float v) {
#pragma unroll
    for (int o = 32; o; o >>= 1) v += __shfl_xor(v, o);
    return v;
}

// Persistent: 256 blocks x 1024 threads, 1 block/CU. Payload traffic is
// lane-contiguous (float4 idx = k*1024 + u). Per-chunk software pipeline:
// each chunk k waits on the prefetch load issued at chunk k of the PREVIOUS
// iteration (~12us earlier -> pre-satisfied), so waves never stall on VMEM
// and the memory queue always holds ~one iteration of loads+stores.
__global__ __launch_bounds__(1024, 4) void cama_kernel(
    const float* __restrict__ bids,   // B,8,16
    const float* __restrict__ allocs, // B,256,8,16
    const float* __restrict__ wvec,   // B,8
    const float* __restrict__ bvec,   // B,256
    const float* __restrict__ tempp,  // 1
    float* __restrict__ out, int Bsz, int iters)
{
    __shared__ float lds_pwT[NAGENTS * MENU];     // 8KB, [n][s^(n<<2)]
    __shared__ float lds_tot[MENU];
    __shared__ float lds_bb[2][MENU];             // double-buffered smalls
    __shared__ __align__(16) float lds_bids[2][NM];
    __shared__ float lds_w[2][NAGENTS];
    __shared__ float lds_ch[SFULL];
    __shared__ __align__(16) float lds_scr[16 * NM];  // 8KB item scratch
    __shared__ float lds_rcs[NAGENTS], lds_rb[NAGENTS], lds_cw[NAGENTS];
    __shared__ float lds_ab;

    const int u = threadIdx.x;       // 0..1023
    const int lane = u & 63;
    const int wave = u >> 6;         // 0..15
    const int n  = (u >> 2) & 7;     // agent owned by this thread
    const int mq = u & 3;            // item-quad owned
    const int su = u >> 5;           // row-within-32-block, 0..31

    float* out_choice = out;                                  // B*257
    float* out_item   = out + (size_t)Bsz * SFULL;            // B*128
    float* out_pay    = out_item + (size_t)Bsz * NM;          // 8*B
    float* out_all    = out_pay + (size_t)NAGENTS * Bsz;      // B*257*128
    float4* out_all4  = (float4*)out_all;
    const float4* all4 = (const float4*)allocs;

    const float temp = tempp[0];
    size_t a = (size_t)blockIdx.x * iters;

    float4 Pf[8];   // prefetched payload (next auction)

    // ---- prologue: payload + smalls for first auction ----
    {
        float rbb = 0.f, rbid = 0.f, rw = 0.f;
        if (u < MENU)    rbb  = bvec[a * MENU + u];
        if (u < NM)      rbid = bids[a * NM + u];
        if (u < NAGENTS) rw   = wvec[a * NAGENTS + u];
#pragma unroll
        for (int k = 0; k < 8; ++k)
            Pf[k] = all4[a * 8192 + (k << 10) + u];
        if (u < MENU)    lds_bb[0][u]   = rbb;
        if (u < NM)      lds_bids[0][u] = rbid;
        if (u < NAGENTS) lds_w[0][u]    = rw;
    }
    BAR();

    for (int it = 0; it < iters; ++it) {
        const int p = it & 1;
        // clamped next-auction index: last iteration re-reads current (valid,
        // unused) to keep control flow & codegen uniform
        const size_t an = (it + 1 < iters) ? a + 1 : a;

        // smalls for this iteration (staged to LDS last iteration)
        const float4 q4 = ((const float4*)&lds_bids[p][0])[u & 31]; // q[n][mq]
        const float w_n = lds_w[p][n];

        // ---- chunked pipeline: per k = consume / prefetch / store / welfare ----
        float4 Sf[8];
#pragma unroll
        for (int k = 0; k < 8; ++k) {
            Sf[k] = Pf[k];                               // wait: load from LAST iter
            Pf[k] = all4[an * 8192 + (k << 10) + u];     // issue next-iter load
            out_all4[a * 8224 + (k << 10) + u] = Sf[k];  // issue copy-out store
            const int s = (k << 5) + su;
            float util = Sf[k].x*q4.x + Sf[k].y*q4.y + Sf[k].z*q4.z + Sf[k].w*q4.w;
            util += __shfl_xor(util, 1);
            util += __shfl_xor(util, 2);     // full item-dot for (s,n)
            float pwv = w_n * util;
            if (mq == 0) lds_pwT[(n << 8) + (s ^ (n << 2))] = pwv;
            float t = pwv;
            t += __shfl_xor(t, 4);
            t += __shfl_xor(t, 8);
            t += __shfl_xor(t, 16);          // sum over agents
            if ((lane & 31) == 0) lds_tot[s] = t;
        }
        if (u < 32)
            out_all4[a * 8224 + 8192 + u] = make_float4(0.f, 0.f, 0.f, 0.f);

        // prefetch next smalls (registers; staged to LDS after b2)
        float rbb2 = 0.f, rbid2 = 0.f, rw2 = 0.f;
        if (u < MENU)    rbb2  = bvec[an * MENU + u];
        if (u < NM)      rbid2 = bids[an * NM + u];
        if (u < NAGENTS) rw2   = wvec[an * NAGENTS + u];
        BAR();   // b1: pwT/tot ready

        // ---- Round A: full softmax (wave 0) + 8 LOO softmaxes (waves 1..8) ----
        if (wave == 0) {
            float xs[4], bl[4], es[4];
            float mx = -1e30f;
#pragma unroll
            for (int c = 0; c < 4; ++c) {
                int v = (c << 6) | lane;
                bl[c] = lds_bb[p][v];
                float x = (lds_tot[v] + bl[c]) * temp;
                xs[c] = x; mx = fmaxf(mx, x);
            }
            mx = fmaxf(wredmax(mx), 0.f);   // null entry has x=0
            float se = 0.f, sab = 0.f;
#pragma unroll
            for (int c = 0; c < 4; ++c) { es[c] = __expf(xs[c] - mx); se += es[c]; sab += es[c] * bl[c]; }
            float en = __expf(-mx);
            se = wredsum(se) + en;
            sab = wredsum(sab);
            float inv = 1.f / se;
#pragma unroll
            for (int c = 0; c < 4; ++c) {
                int v = (c << 6) | lane;
                float chv = es[c] * inv;
                lds_ch[v] = chv;
                out_choice[a * SFULL + v] = chv;
            }
            if (lane == 0) {
                float chn = en * inv;
                lds_ch[MENU] = chn;
                out_choice[a * SFULL + MENU] = chn;
                lds_ab = sab * inv;
            }
        } else if (wave <= 8) {
            const int i = wave - 1;
            float xs[4], trs[4], bl[4];
            float mx = -1e30f;
#pragma unroll
            for (int c = 0; c < 4; ++c) {
                int v = (c << 6) | lane;
                bl[c] = lds_bb[p][v];
                float tr = lds_tot[v] - lds_pwT[(i << 8) + (v ^ (i << 2))];
                trs[c] = tr;
                float x = (tr + bl[c]) * temp;
                xs[c] = x; mx = fmaxf(mx, x);
            }
            mx = fmaxf(wredmax(mx), 0.f);
            float se = 0.f, s1 = 0.f, s2 = 0.f;
#pragma unroll
            for (int c = 0; c < 4; ++c) {
                float e = __expf(xs[c] - mx);
                se += e; s1 += e * trs[c]; s2 += e * bl[c];
            }
            se = wredsum(se) + __expf(-mx);
            s1 = wredsum(s1);
            s2 = wredsum(s2);
            if (lane == 0) { lds_rcs[i] = s1 / se; lds_rb[i] = s2 / se; }
        }
        BAR();   // b2: ch/rcs/rb/ab ready

        // ---- chosen welfare per agent (waves 0..7) ----
        if (wave < 8) {
            const int i = wave;
            float cwv = 0.f;
#pragma unroll
            for (int c = 0; c < 4; ++c) {
                int v = (c << 6) | lane;
                cwv += lds_ch[v] * lds_pwT[(i << 8) + (v ^ (i << 2))];
            }
            cwv = wredsum(cwv);
            if (lane == 0) lds_cw[i] = cwv;
        }
        // ---- item allocation partials from Sf registers ----
        {
            float ax = 0.f, ay = 0.f, az = 0.f, aw = 0.f;
#pragma unroll
            for (int k = 0; k < 8; ++k) {
                float chv = lds_ch[(k << 5) + su];
                ax += Sf[k].x * chv; ay += Sf[k].y * chv;
                az += Sf[k].z * chv; aw += Sf[k].w * chv;
            }
            ax += __shfl_xor(ax, 32);
            ay += __shfl_xor(ay, 32);
            az += __shfl_xor(az, 32);
            aw += __shfl_xor(aw, 32);
            if (lane < 32)   // word index = n*16 + m within this wave's slice
                ((float4*)lds_scr)[(wave << 5) + lane] = make_float4(ax, ay, az, aw);
        }
        // ---- stage next smalls (their loads are long complete) ----
        if (u < MENU)    lds_bb[p ^ 1][u]   = rbb2;
        if (u < NM)      lds_bids[p ^ 1][u] = rbid2;
        if (u < NAGENTS) lds_w[p ^ 1][u]    = rw2;
        BAR();   // b3: scr/cw ready; pwT/tot/ch safe to overwrite next iter

        // ---- item final reduce + payments ----
        if (u < NM) {
            float s = 0.f;
#pragma unroll
            for (int w = 0; w < 16; ++w) s += lds_scr[(w << 7) + u];
            out_item[a * NM + u] = s;
        }
        if (u < NAGENTS) {
            float ctot = 0.f;
#pragma unroll
            for (int k = 0; k < NAGENTS; ++k) ctot += lds_cw[k];
            float pay = (lds_rcs[u] + lds_rb[u] - (ctot - lds_cw[u]) - lds_ab)
                        / lds_w[p][u];
            out_pay[(size_t)u * Bsz + a] = pay;
        }
        a = a + 1;
    }
}

extern "C" void kernel_launch(void* const* d_in, const int* in_sizes, int n_in,
                              void* d_out, int out_size, void* d_ws, size_t ws_size,
                              hipStream_t stream) {
    const float* bids   = (const float*)d_in[0];
    const float* allocs = (const float*)d_in[1];
    const float* wvec   = (const float*)d_in[2];
    const float* bvec   = (const float*)d_in[3];
    const float* tempp  = (const float*)d_in[4];
    float* out = (float*)d_out;
    const int Bsz = in_sizes[0] / NM;          // 4096
    const int nblocks = 256;                   // 1 per CU
    const int iters = Bsz / nblocks;           // 16
    cama_kernel<<<nblocks, 1024, 0, stream>>>(bids, allocs, wvec, bvec, tempp,
                                              out, Bsz, iters);
}

// Round 7
// 235.277 us; speedup vs baseline: 1.1033x; 1.1033x over previous
//
#include <hip/hip_runtime.h>

#define NAGENTS 8
#define NM 128          // NAGENTS*MITEMS
#define MENU 256
#define SFULL 257       // MENU + null entry

// Raw barrier: wait LDS ops only (no vmcnt drain — copy-out stores and any
// in-flight loads keep flying across phases).
#define BAR() asm volatile("s_waitcnt lgkmcnt(0)\n\ts_barrier" ::: "memory")

__device__ __forceinline__ float wredmax(float v) {
#pragma unroll
    for (int o = 32; o; o >>= 1) v = fmaxf(v, __shfl_xor(v, o));
    return v;
}
__device__ __forceinline__ float wredsum(float v) {
#pragma unroll
    for (int o = 32; o; o >>= 1) v += __shfl_xor(v, o);
    return v;
}

// 256 threads/block, one auction per block, 8 blocks/CU (32 waves/CU).
// Payload is streamed ONCE: load -> copy-out store -> welfare dot ->
// online-softmax accumulate (flash-style) for item_allocation. Nothing
// holds the 128KB payload, so occupancy is copy-kernel-grade and TLP
// keeps the HBM pipe saturated.
__global__ __launch_bounds__(256, 8) void cama_kernel(
    const float* __restrict__ bids,   // B,8,16
    const float* __restrict__ allocs, // B,256,8,16
    const float* __restrict__ wvec,   // B,8
    const float* __restrict__ bvec,   // B,256
    const float* __restrict__ tempp,  // 1
    float* __restrict__ out, int Bsz)
{
    __shared__ float lds_pwT[NAGENTS * MENU];        // 8KB, [n][s^(n<<2)]
    __shared__ float lds_tot[MENU];                  // 1KB
    __shared__ float lds_bb[MENU];                   // 1KB
    __shared__ float lds_ch[SFULL];
    __shared__ __align__(16) float4 lds_accs[4][32]; // 2KB online-acc merge
    __shared__ __align__(8)  float2 lds_mz[4][32];   // 1KB (m, Z) merge
    __shared__ float lds_rcs[NAGENTS], lds_rb[NAGENTS], lds_cw[NAGENTS];
    __shared__ float lds_ab;

    const int u = threadIdx.x;    // 0..255
    const int lane = u & 63;
    const int wave = u >> 6;      // 0..3
    const int c = u & 31;         // float4 column: n = c>>2, item-quad = c&3
    const int n = c >> 2;
    const int su = u >> 5;        // 0..7: row subset (s = 8k + su)
    const size_t bb_ = (size_t)blockIdx.x;

    float* out_choice = out;                                  // B*257
    float* out_item   = out + (size_t)Bsz * SFULL;            // B*128
    float* out_pay    = out_item + (size_t)Bsz * NM;          // 8*B
    float* out_all    = out_pay + (size_t)NAGENTS * Bsz;      // B*257*128
    float4* out_all4  = (float4*)out_all + bb_ * 8224;
    const float4* src4 = (const float4*)allocs + bb_ * 8192;

    const float temp = tempp[0];
    lds_bb[u] = bvec[bb_ * MENU + u];                    // stage b (256 = blockDim)
    const float4 q4 = ((const float4*)(bids + bb_ * NM))[c];   // L1 broadcast
    const float w_n = wvec[bb_ * NAGENTS + n];
    BAR();   // bb staged

    // ---- pass 1: single streaming pass over the payload ----
    float m_r = -1e30f, Z_r = 0.f;
    float4 acc = make_float4(0.f, 0.f, 0.f, 0.f);
#pragma unroll 4
    for (int k = 0; k < 32; ++k) {
        const int idx = (k << 8) + u;              // lane-contiguous float4
        float4 a4 = src4[idx];
        out_all4[idx] = a4;                        // copy-out (never re-read)
        const int s = (k << 3) + su;
        float util = a4.x*q4.x + a4.y*q4.y + a4.z*q4.z + a4.w*q4.w;
        util += __shfl_xor(util, 1);
        util += __shfl_xor(util, 2);               // full item-dot for (s,n)
        float pwv = w_n * util;
        if ((u & 3) == 0) lds_pwT[(n << 8) + (s ^ (n << 2))] = pwv;
        float t = pwv;
        t += __shfl_xor(t, 4);
        t += __shfl_xor(t, 8);
        t += __shfl_xor(t, 16);                    // total welfare, all lanes
        if (c == 0) lds_tot[s] = t;
        // online softmax accumulate for item_allocation
        float x = (t + lds_bb[s]) * temp;
        float mn = fmaxf(m_r, x);
        float sc = __expf(m_r - mn);               // 1.0 when no new max
        float p  = __expf(x - mn);
        Z_r = Z_r * sc + p;
        acc.x = acc.x * sc + p * a4.x;
        acc.y = acc.y * sc + p * a4.y;
        acc.z = acc.z * sc + p * a4.z;
        acc.w = acc.w * sc + p * a4.w;
        m_r = mn;
    }
    if (u < 32)
        out_all4[8192 + u] = make_float4(0.f, 0.f, 0.f, 0.f);   // null row

    // pair-merge su <-> su^1 (halves of each wave)
    {
        float mo = __shfl_xor(m_r, 32);
        float Zo = __shfl_xor(Z_r, 32);
        float ax = __shfl_xor(acc.x, 32), ay = __shfl_xor(acc.y, 32);
        float az = __shfl_xor(acc.z, 32), aw = __shfl_xor(acc.w, 32);
        float mn = fmaxf(m_r, mo);
        float s0 = __expf(m_r - mn), s1 = __expf(mo - mn);
        Z_r = Z_r * s0 + Zo * s1;
        acc.x = acc.x * s0 + ax * s1;
        acc.y = acc.y * s0 + ay * s1;
        acc.z = acc.z * s0 + az * s1;
        acc.w = acc.w * s0 + aw * s1;
        if (lane < 32) {
            lds_accs[wave][c] = acc;
            lds_mz[wave][c] = make_float2(mn, Z_r);
        }
    }
    BAR();   // b1: pwT/tot/accs ready

    // ---- softmax tasks: t=0 full, t=1..8 leave-one-out (i=t-1); 4 waves ----
    for (int t = wave; t < 9; t += 4) {
        if (t == 0) {
            float xs[4], bl[4], es[4];
            float mx = -1e30f;
#pragma unroll
            for (int c4 = 0; c4 < 4; ++c4) {
                int v = (c4 << 6) | lane;
                bl[c4] = lds_bb[v];
                float x = (lds_tot[v] + bl[c4]) * temp;
                xs[c4] = x; mx = fmaxf(mx, x);
            }
            mx = fmaxf(wredmax(mx), 0.f);          // null entry x=0
            float se = 0.f, sab = 0.f;
#pragma unroll
            for (int c4 = 0; c4 < 4; ++c4) {
                es[c4] = __expf(xs[c4] - mx);
                se += es[c4]; sab += es[c4] * bl[c4];
            }
            float en = __expf(-mx);
            se = wredsum(se) + en;
            sab = wredsum(sab);
            float inv = 1.f / se;
#pragma unroll
            for (int c4 = 0; c4 < 4; ++c4) {
                int v = (c4 << 6) | lane;
                float chv = es[c4] * inv;
                lds_ch[v] = chv;
                out_choice[bb_ * SFULL + v] = chv;
            }
            if (lane == 0) {
                float chn = en * inv;
                lds_ch[MENU] = chn;
                out_choice[bb_ * SFULL + MENU] = chn;
                lds_ab = sab * inv;
            }
        } else {
            const int i = t - 1;
            float xs[4], trs[4], bl[4];
            float mx = -1e30f;
#pragma unroll
            for (int c4 = 0; c4 < 4; ++c4) {
                int v = (c4 << 6) | lane;
                bl[c4] = lds_bb[v];
                float tr = lds_tot[v] - lds_pwT[(i << 8) + (v ^ (i << 2))];
                trs[c4] = tr;
                float x = (tr + bl[c4]) * temp;
                xs[c4] = x; mx = fmaxf(mx, x);
            }
            mx = fmaxf(wredmax(mx), 0.f);
            float se = 0.f, s1 = 0.f, s2 = 0.f;
#pragma unroll
            for (int c4 = 0; c4 < 4; ++c4) {
                float e = __expf(xs[c4] - mx);
                se += e; s1 += e * trs[c4]; s2 += e * bl[c4];
            }
            se = wredsum(se) + __expf(-mx);
            s1 = wredsum(s1);
            s2 = wredsum(s2);
            if (lane == 0) { lds_rcs[i] = s1 / se; lds_rb[i] = s2 / se; }
        }
    }
    BAR();   // b2: ch/rcs/rb/ab ready

    // ---- chosen welfare (2 agents per wave) ----
    for (int i = wave; i < NAGENTS; i += 4) {
        float cwv = 0.f;
#pragma unroll
        for (int c4 = 0; c4 < 4; ++c4) {
            int v = (c4 << 6) | lane;
            cwv += lds_ch[v] * lds_pwT[(i << 8) + (v ^ (i << 2))];
        }
        cwv = wredsum(cwv);
        if (lane == 0) lds_cw[i] = cwv;
    }
    // ---- item_allocation: final cross-wave merge + null + normalize ----
    if (u < 32) {
        float4 A = lds_accs[0][u];
        float2 mz = lds_mz[0][u];
        float M = mz.x, Z = mz.y;
#pragma unroll
        for (int j = 1; j < 4; ++j) {
            float4 Aj = lds_accs[j][u];
            float2 mzj = lds_mz[j][u];
            float mn = fmaxf(M, mzj.x);
            float s0 = __expf(M - mn), s1 = __expf(mzj.x - mn);
            Z = Z * s0 + mzj.y * s1;
            A.x = A.x * s0 + Aj.x * s1;
            A.y = A.y * s0 + Aj.y * s1;
            A.z = A.z * s0 + Aj.z * s1;
            A.w = A.w * s0 + Aj.w * s1;
            M = mn;
        }
        float mn = fmaxf(M, 0.f);                  // null entry
        float s0 = __expf(M - mn);
        Z = Z * s0 + __expf(-mn);
        float inv = 1.f / Z;
        s0 *= inv;
        ((float4*)(out_item + bb_ * NM))[u] =
            make_float4(A.x * s0, A.y * s0, A.z * s0, A.w * s0);
    }
    BAR();   // b3: cw ready

    // ---- payments, layout (n, B) ----
    if (u < NAGENTS) {
        float ctot = 0.f;
#pragma unroll
        for (int k = 0; k < NAGENTS; ++k) ctot += lds_cw[k];
        float pay = (lds_rcs[u] + lds_rb[u] - (ctot - lds_cw[u]) - lds_ab)
                    / wvec[bb_ * NAGENTS + u];
        out_pay[(size_t)u * Bsz + bb_] = pay;
    }
}

extern "C" void kernel_launch(void* const* d_in, const int* in_sizes, int n_in,
                              void* d_out, int out_size, void* d_ws, size_t ws_size,
                              hipStream_t stream) {
    const float* bids   = (const float*)d_in[0];
    const float* allocs = (const float*)d_in[1];
    const float* wvec   = (const float*)d_in[2];
    const float* bvec   = (const float*)d_in[3];
    const float* tempp  = (const float*)d_in[4];
    float* out = (float*)d_out;
    const int Bsz = in_sizes[0] / NM;          // 4096
    cama_kernel<<<Bsz, 256, 0, stream>>>(bids, allocs, wvec, bvec, tempp,
                                         out, Bsz);
}